// Round 1
// baseline (187.917 us; speedup 1.0000x reference)
//
#include <hip/hip_runtime.h>
#include <math.h>

// Problem constants (from reference)
#define Bn   16
#define Cn   64
#define Nn   65536        // H*W = 256*256
#define Sn   64           // n-slices per batch for gram kernel
#define Ln   (Nn / Sn)    // 1024 elements per block
#define REDn 16

typedef float    f32x4  __attribute__((ext_vector_type(4)));
typedef float    f32x16 __attribute__((ext_vector_type(16)));
typedef _Float16 f16x8  __attribute__((ext_vector_type(8)));

// ---------------------------------------------------------------------------
// Kernel 1: per (batch, n-slice) block computes
//   so_part[c] = sum_d (sum_{n in slice} x[b,c,n]*x[b,d,n]) * Wrow[c,d]
//   pool_part[c] = sum_{n in slice} x[b,c,n]
// Gram via f16 MFMA (fp32 accumulate), direct-from-global fragments.
// ---------------------------------------------------------------------------
__global__ __launch_bounds__(256) void gram_pool_kernel(
    const float* __restrict__ x, const float* __restrict__ Wrow,
    float* __restrict__ part) {
  const int b    = blockIdx.x / Sn;
  const int s    = blockIdx.x % Sn;
  const int tid  = threadIdx.x;
  const int wid  = tid >> 6;
  const int lane = tid & 63;
  const int l31  = lane & 31;
  const int lhi  = lane >> 5;   // 0 or 1: which k-subgroup this lane covers

  const float* xb = x + (size_t)b * Cn * Nn;
  const float* p0 = xb + (size_t)l31 * Nn;          // row group 0: rows 0..31
  const float* p1 = xb + (size_t)(l31 + 32) * Nn;   // row group 1: rows 32..63

  // each of the 4 waves takes a disjoint quarter of this block's n-range
  const int kbeg = s * Ln + wid * (Ln / 4);
  const int kend = kbeg + (Ln / 4);

  f32x16 acc00, acc01, acc11;
#pragma unroll
  for (int r = 0; r < 16; ++r) { acc00[r] = 0.f; acc01[r] = 0.f; acc11[r] = 0.f; }
  float pool0 = 0.f, pool1 = 0.f;

  for (int k = kbeg; k < kend; k += 16) {
    const int off = k + lhi * 8;
    f32x4 a0 = *(const f32x4*)(p0 + off);
    f32x4 a1 = *(const f32x4*)(p0 + off + 4);
    f32x4 c0 = *(const f32x4*)(p1 + off);
    f32x4 c1 = *(const f32x4*)(p1 + off + 4);

    pool0 += (a0[0] + a0[1]) + (a0[2] + a0[3]) + (a1[0] + a1[1]) + (a1[2] + a1[3]);
    pool1 += (c0[0] + c0[1]) + (c0[2] + c0[3]) + (c1[0] + c1[1]) + (c1[2] + c1[3]);

    f16x8 af, bf;
#pragma unroll
    for (int r = 0; r < 4; ++r) {
      af[r]     = (_Float16)a0[r];
      af[r + 4] = (_Float16)a1[r];
      bf[r]     = (_Float16)c0[r];
      bf[r + 4] = (_Float16)c1[r];
    }
    // Gram quadrants: (0,0), (0,1), (1,1); (1,0) is the transpose of (0,1).
    acc00 = __builtin_amdgcn_mfma_f32_32x32x16_f16(af, af, acc00, 0, 0, 0);
    acc01 = __builtin_amdgcn_mfma_f32_32x32x16_f16(af, bf, acc01, 0, 0, 0);
    acc11 = __builtin_amdgcn_mfma_f32_32x32x16_f16(bf, bf, acc11, 0, 0, 0);
  }

  // pool: lane l and lane l+32 hold partials for the same row (disjoint k)
  pool0 += __shfl_down(pool0, 32);
  pool1 += __shfl_down(pool1, 32);

  __shared__ float corr_lds[Cn][Cn + 1];   // +1 pad: epilogue reads column-wise
  __shared__ float pool_lds0[4][32];
  __shared__ float pool_lds1[4][32];

  if (lane < 32) {
    pool_lds0[wid][lane] = pool0;   // rows 0..31
    pool_lds1[wid][lane] = pool1;   // rows 32..63
  }

  // sequential wave accumulation of the 64x64 corr tile into LDS
  for (int w = 0; w < 4; ++w) {
    if (wid == w) {
#pragma unroll
      for (int r = 0; r < 16; ++r) {
        // verified C/D layout for 32x32 MFMA: col=lane&31, row=(r&3)+8*(r>>2)+4*(lane>>5)
        const int i = (r & 3) + 8 * (r >> 2) + 4 * lhi;
        const int j = l31;
        if (w == 0) {
          corr_lds[i][j]           = acc00[r];
          corr_lds[i][j + 32]      = acc01[r];
          corr_lds[j + 32][i]      = acc01[r];   // symmetric mirror
          corr_lds[i + 32][j + 32] = acc11[r];
        } else {
          corr_lds[i][j]           += acc00[r];
          corr_lds[i][j + 32]      += acc01[r];
          corr_lds[j + 32][i]      += acc01[r];
          corr_lds[i + 32][j + 32] += acc11[r];
        }
      }
    }
    __syncthreads();
  }

  if (tid < Cn) {
    const float* wr = Wrow + tid * Cn;
    float so = 0.f;
#pragma unroll 8
    for (int d = 0; d < Cn; ++d) so += corr_lds[tid][d] * wr[d];
    float pp = 0.f;
    if (tid < 32) {
#pragma unroll
      for (int w = 0; w < 4; ++w) pp += pool_lds0[w][tid];
    } else {
#pragma unroll
      for (int w = 0; w < 4; ++w) pp += pool_lds1[w][tid - 32];
    }
    float* o = part + (size_t)(b * Sn + s) * (2 * Cn);
    o[tid]      = so;   // unnormalized so partial
    o[Cn + tid] = pp;   // unnormalized pool partial
  }
}

// ---------------------------------------------------------------------------
// Kernel 2: per-batch reduce partials + tiny MLP -> gate g[b,c]
// ---------------------------------------------------------------------------
__global__ __launch_bounds__(64) void se_kernel(
    const float* __restrict__ part, const float* __restrict__ brow,
    const float* __restrict__ W1, const float* __restrict__ b1,
    const float* __restrict__ W2, const float* __restrict__ b2,
    float* __restrict__ g) {
  const int b = blockIdx.x;
  const int t = threadIdx.x;   // 0..63

  __shared__ float y_s[Cn];
  __shared__ float z_s[REDn];

  float so = 0.f, pl = 0.f;
  for (int s = 0; s < Sn; ++s) {
    const float* p = part + (size_t)(b * Sn + s) * (2 * Cn);
    so += p[t];
    pl += p[Cn + t];
  }
  // y = pool + so ; pool = pl/N ; so = so/N + brow
  y_s[t] = (so + pl) * (1.0f / (float)Nn) + brow[t];
  __syncthreads();

  if (t < REDn) {
    float z = b1[t];
#pragma unroll 8
    for (int c = 0; c < Cn; ++c) z += W1[t * Cn + c] * y_s[c];
    z_s[t] = fmaxf(z, 0.f);
  }
  __syncthreads();

  float a = b2[t];
#pragma unroll
  for (int r = 0; r < REDn; ++r) a += W2[t * REDn + r] * z_s[r];
  g[b * Cn + t] = 1.0f / (1.0f + expf(-a));
}

// ---------------------------------------------------------------------------
// Kernel 3: out[b,c,n] = x[b,c,n] * g[b,c]   (float4 streaming)
// ---------------------------------------------------------------------------
__global__ __launch_bounds__(256) void scale_kernel(
    const float* __restrict__ x, const float* __restrict__ g,
    float* __restrict__ out) {
  const size_t total4 = (size_t)Bn * Cn * Nn / 4;
  const size_t stride = (size_t)gridDim.x * blockDim.x;
  for (size_t idx = (size_t)blockIdx.x * blockDim.x + threadIdx.x;
       idx < total4; idx += stride) {
    const float gg = g[idx >> 14];   // Nn/4 = 16384 float4 per (b,c)
    f32x4 v = ((const f32x4*)x)[idx];
    v *= gg;
    ((f32x4*)out)[idx] = v;
  }
}

// ---------------------------------------------------------------------------
extern "C" void kernel_launch(void* const* d_in, const int* in_sizes, int n_in,
                              void* d_out, int out_size, void* d_ws, size_t ws_size,
                              hipStream_t stream) {
  const float* x    = (const float*)d_in[0];
  const float* Wrow = (const float*)d_in[1];
  const float* brow = (const float*)d_in[2];
  const float* W1   = (const float*)d_in[3];
  const float* b1   = (const float*)d_in[4];
  const float* W2   = (const float*)d_in[5];
  const float* b2   = (const float*)d_in[6];
  float* out = (float*)d_out;

  // Scratch: partials live in the FRONT of d_out (512 KB, fully overwritten by
  // scale_kernel afterwards); gate g (4 KB) lives in d_ws.
  float* part = (float*)d_out;
  float* g    = (float*)d_ws;

  gram_pool_kernel<<<Bn * Sn, 256, 0, stream>>>(x, Wrow, part);
  se_kernel<<<Bn, 64, 0, stream>>>(part, brow, W1, b1, W2, b2, g);
  scale_kernel<<<2048, 256, 0, stream>>>(x, g, out);
}

// Round 3
// 174.285 us; speedup vs baseline: 1.0782x; 1.0782x over previous
//
#include <hip/hip_runtime.h>
#include <math.h>

// Problem constants (from reference)
#define Bn   16
#define Cn   64
#define Nn   65536        // H*W = 256*256
#define Sn   64           // n-slices per batch for gram kernel
#define Ln   (Nn / Sn)    // 1024 elements per block
#define REDn 16

typedef float    f32x4  __attribute__((ext_vector_type(4)));
typedef float    f32x16 __attribute__((ext_vector_type(16)));
typedef __fp16   fp16x2 __attribute__((ext_vector_type(2)));
typedef _Float16 f16x8  __attribute__((ext_vector_type(8)));

union half8_u {
  f16x8  v;
  fp16x2 h[4];
};

// ---------------------------------------------------------------------------
// Kernel 1: per (batch, n-slice) block computes
//   so_part[c] = sum_d (sum_{n in slice} x[b,c,n]*x[b,d,n]) * Wrow[c,d]
//   pool_part[c] = sum_{n in slice} x[b,c,n]
// Gram via f16 MFMA (fp32 accumulate), direct-from-global fragments.
// k-loop unrolled x2: 8 independent 16B loads in flight per lane per iter
// (latency hiding), conversions via packed cvt_pkrtz.
// ---------------------------------------------------------------------------
__global__ __launch_bounds__(256, 4) void gram_pool_kernel(
    const float* __restrict__ x, const float* __restrict__ Wrow,
    float* __restrict__ part) {
  const int b    = blockIdx.x / Sn;
  const int s    = blockIdx.x % Sn;
  const int tid  = threadIdx.x;
  const int wid  = tid >> 6;
  const int lane = tid & 63;
  const int l31  = lane & 31;
  const int lhi  = lane >> 5;   // 0 or 1: which k-subgroup this lane covers

  const float* xb = x + (size_t)b * Cn * Nn;
  const float* p0 = xb + (size_t)l31 * Nn;          // row group 0: rows 0..31
  const float* p1 = xb + (size_t)(l31 + 32) * Nn;   // row group 1: rows 32..63

  // each of the 4 waves takes a disjoint quarter of this block's n-range
  const int kbeg = s * Ln + wid * (Ln / 4);
  const int kend = kbeg + (Ln / 4);   // 256 k-elements per wave

  f32x16 acc00, acc01, acc11;
#pragma unroll
  for (int r = 0; r < 16; ++r) { acc00[r] = 0.f; acc01[r] = 0.f; acc11[r] = 0.f; }
  float pool0 = 0.f, pool1 = 0.f;

  for (int k = kbeg; k < kend; k += 32) {   // two 16-wide k-tiles per iteration
    f32x4 a0[2], a1[2], c0[2], c1[2];
#pragma unroll
    for (int t = 0; t < 2; ++t) {
      const int off = k + t * 16 + lhi * 8;
      a0[t] = *(const f32x4*)(p0 + off);
      a1[t] = *(const f32x4*)(p0 + off + 4);
      c0[t] = *(const f32x4*)(p1 + off);
      c1[t] = *(const f32x4*)(p1 + off + 4);
    }
#pragma unroll
    for (int t = 0; t < 2; ++t) {
      pool0 += (a0[t][0] + a0[t][1]) + (a0[t][2] + a0[t][3])
             + (a1[t][0] + a1[t][1]) + (a1[t][2] + a1[t][3]);
      pool1 += (c0[t][0] + c0[t][1]) + (c0[t][2] + c0[t][3])
             + (c1[t][0] + c1[t][1]) + (c1[t][2] + c1[t][3]);

      half8_u au, bu;
      au.h[0] = __builtin_amdgcn_cvt_pkrtz(a0[t][0], a0[t][1]);
      au.h[1] = __builtin_amdgcn_cvt_pkrtz(a0[t][2], a0[t][3]);
      au.h[2] = __builtin_amdgcn_cvt_pkrtz(a1[t][0], a1[t][1]);
      au.h[3] = __builtin_amdgcn_cvt_pkrtz(a1[t][2], a1[t][3]);
      bu.h[0] = __builtin_amdgcn_cvt_pkrtz(c0[t][0], c0[t][1]);
      bu.h[1] = __builtin_amdgcn_cvt_pkrtz(c0[t][2], c0[t][3]);
      bu.h[2] = __builtin_amdgcn_cvt_pkrtz(c1[t][0], c1[t][1]);
      bu.h[3] = __builtin_amdgcn_cvt_pkrtz(c1[t][2], c1[t][3]);

      // Gram quadrants: (0,0), (0,1), (1,1); (1,0) is the transpose of (0,1).
      acc00 = __builtin_amdgcn_mfma_f32_32x32x16_f16(au.v, au.v, acc00, 0, 0, 0);
      acc01 = __builtin_amdgcn_mfma_f32_32x32x16_f16(au.v, bu.v, acc01, 0, 0, 0);
      acc11 = __builtin_amdgcn_mfma_f32_32x32x16_f16(bu.v, bu.v, acc11, 0, 0, 0);
    }
  }

  // pool: lane l and lane l+32 hold partials for the same row (disjoint k)
  pool0 += __shfl_down(pool0, 32);
  pool1 += __shfl_down(pool1, 32);

  __shared__ float corr_lds[Cn][Cn + 1];   // +1 pad: epilogue reads column-wise
  __shared__ float pool_lds0[4][32];
  __shared__ float pool_lds1[4][32];

  if (lane < 32) {
    pool_lds0[wid][lane] = pool0;   // rows 0..31
    pool_lds1[wid][lane] = pool1;   // rows 32..63
  }

  // sequential wave accumulation of the 64x64 corr tile into LDS
  for (int w = 0; w < 4; ++w) {
    if (wid == w) {
#pragma unroll
      for (int r = 0; r < 16; ++r) {
        // verified C/D layout for 32x32 MFMA: col=lane&31, row=(r&3)+8*(r>>2)+4*(lane>>5)
        const int i = (r & 3) + 8 * (r >> 2) + 4 * lhi;
        const int j = l31;
        if (w == 0) {
          corr_lds[i][j]           = acc00[r];
          corr_lds[i][j + 32]      = acc01[r];
          corr_lds[j + 32][i]      = acc01[r];   // symmetric mirror
          corr_lds[i + 32][j + 32] = acc11[r];
        } else {
          corr_lds[i][j]           += acc00[r];
          corr_lds[i][j + 32]      += acc01[r];
          corr_lds[j + 32][i]      += acc01[r];
          corr_lds[i + 32][j + 32] += acc11[r];
        }
      }
    }
    __syncthreads();
  }

  if (tid < Cn) {
    const float* wr = Wrow + tid * Cn;
    float so = 0.f;
#pragma unroll 8
    for (int d = 0; d < Cn; ++d) so += corr_lds[tid][d] * wr[d];
    float pp = 0.f;
    if (tid < 32) {
#pragma unroll
      for (int w = 0; w < 4; ++w) pp += pool_lds0[w][tid];
    } else {
#pragma unroll
      for (int w = 0; w < 4; ++w) pp += pool_lds1[w][tid - 32];
    }
    float* o = part + (size_t)(b * Sn + s) * (2 * Cn);
    o[tid]      = so;   // unnormalized so partial
    o[Cn + tid] = pp;   // unnormalized pool partial
  }
}

// ---------------------------------------------------------------------------
// Kernel 2: per-batch reduce partials + tiny MLP -> gate g[b,c]
// ---------------------------------------------------------------------------
__global__ __launch_bounds__(64) void se_kernel(
    const float* __restrict__ part, const float* __restrict__ brow,
    const float* __restrict__ W1, const float* __restrict__ b1,
    const float* __restrict__ W2, const float* __restrict__ b2,
    float* __restrict__ g) {
  const int b = blockIdx.x;
  const int t = threadIdx.x;   // 0..63

  __shared__ float y_s[Cn];
  __shared__ float z_s[REDn];

  float so = 0.f, pl = 0.f;
  for (int s = 0; s < Sn; ++s) {
    const float* p = part + (size_t)(b * Sn + s) * (2 * Cn);
    so += p[t];
    pl += p[Cn + t];
  }
  // y = pool + so ; pool = pl/N ; so = so/N + brow
  y_s[t] = (so + pl) * (1.0f / (float)Nn) + brow[t];
  __syncthreads();

  if (t < REDn) {
    float z = b1[t];
#pragma unroll 8
    for (int c = 0; c < Cn; ++c) z += W1[t * Cn + c] * y_s[c];
    z_s[t] = fmaxf(z, 0.f);
  }
  __syncthreads();

  float a = b2[t];
#pragma unroll
  for (int r = 0; r < REDn; ++r) a += W2[t * REDn + r] * z_s[r];
  g[b * Cn + t] = 1.0f / (1.0f + expf(-a));
}

// ---------------------------------------------------------------------------
// Kernel 3: out[b,c,n] = x[b,c,n] * g[b,c]   (float4 streaming)
// ---------------------------------------------------------------------------
__global__ __launch_bounds__(256) void scale_kernel(
    const float* __restrict__ x, const float* __restrict__ g,
    float* __restrict__ out) {
  const size_t total4 = (size_t)Bn * Cn * Nn / 4;
  const size_t stride = (size_t)gridDim.x * blockDim.x;
  for (size_t idx = (size_t)blockIdx.x * blockDim.x + threadIdx.x;
       idx < total4; idx += stride) {
    const float gg = g[idx >> 14];   // Nn/4 = 16384 float4 per (b,c)
    f32x4 v = ((const f32x4*)x)[idx];
    v *= gg;
    ((f32x4*)out)[idx] = v;
  }
}

// ---------------------------------------------------------------------------
extern "C" void kernel_launch(void* const* d_in, const int* in_sizes, int n_in,
                              void* d_out, int out_size, void* d_ws, size_t ws_size,
                              hipStream_t stream) {
  const float* x    = (const float*)d_in[0];
  const float* Wrow = (const float*)d_in[1];
  const float* brow = (const float*)d_in[2];
  const float* W1   = (const float*)d_in[3];
  const float* b1   = (const float*)d_in[4];
  const float* W2   = (const float*)d_in[5];
  const float* b2   = (const float*)d_in[6];
  float* out = (float*)d_out;

  // Scratch: partials live in the FRONT of d_out (512 KB, fully overwritten by
  // scale_kernel afterwards); gate g (4 KB) lives in d_ws.
  float* part = (float*)d_out;
  float* g    = (float*)d_ws;

  gram_pool_kernel<<<Bn * Sn, 256, 0, stream>>>(x, Wrow, part);
  se_kernel<<<Bn, 64, 0, stream>>>(part, brow, W1, b1, W2, b2, g);
  scale_kernel<<<2048, 256, 0, stream>>>(x, g, out);
}